// Round 1
// baseline (1134.236 us; speedup 1.0000x reference)
//
#include <hip/hip_runtime.h>

#define SUB_NO 20
#define E_NO   2000
#define I_NO   500
#define T_NO   201
#define BATCH  4
#define T_DATA 20000

#define WARM   (T_NO - 1)      // 200
#define CCHUNK 120
#define XROW   (WARM + CCHUNK) // 320
#define XPAD   (XROW + 1)      // 321 (odd stride -> no LDS bank aliasing)

// ---------------- K0: one-hot -> index tables ----------------
__global__ void k_tables(const float* __restrict__ Ce, const float* __restrict__ Ci,
                         unsigned char* __restrict__ idx_e, unsigned char* __restrict__ idx_i) {
    int e = blockIdx.x * blockDim.x + threadIdx.x;
    if (e < E_NO) {
        int s = 0;
        for (int k = 0; k < SUB_NO; ++k) if (Ce[k * E_NO + e] != 0.0f) s = k;
        idx_e[e] = (unsigned char)s;
    }
    if (e < I_NO) {
        int s = 0;
        for (int k = 0; k < SUB_NO; ++k) if (Ci[k * I_NO + e] != 0.0f) s = k;
        idx_i[e] = (unsigned char)s;
    }
}

// ---------------- K1: segmented sum (the 800MB streamer) ----------------
// grid (ceil(T/64), BATCH), block 256. Wave w = e-slice w; lane = t within 64-t tile.
__global__ __launch_bounds__(256) void k_segsum(
    const float* __restrict__ S_e, const float* __restrict__ S_i,
    const unsigned char* __restrict__ idx_e, const unsigned char* __restrict__ idx_i,
    float* __restrict__ syn_e, float* __restrict__ syn_i) {
    __shared__ float bins_e[4][SUB_NO][64];
    __shared__ float bins_i[4][SUB_NO][64];
    __shared__ __align__(4) unsigned char tab_e[E_NO];
    __shared__ __align__(4) unsigned char tab_i[I_NO];

    const int tid  = threadIdx.x;
    const int w    = tid >> 6;
    const int lane = tid & 63;
    const int b    = blockIdx.y;
    const int t0   = blockIdx.x * 64;
    const int t    = t0 + lane;

    for (int i = tid; i < 4 * SUB_NO * 64; i += 256) {
        (&bins_e[0][0][0])[i] = 0.0f;
        (&bins_i[0][0][0])[i] = 0.0f;
    }
    for (int i = tid; i < E_NO; i += 256) tab_e[i] = idx_e[i];
    for (int i = tid; i < I_NO; i += 256) tab_i[i] = idx_i[i];
    __syncthreads();

    if (t < T_DATA) {
        // E: 2000 floats/row = 500 float4; wave w handles [w*125, w*125+125)
        const float4*   row   = (const float4*)(S_e + (size_t)(b * T_DATA + t) * E_NO);
        const unsigned* tab32 = (const unsigned*)tab_e;
        const int j1 = w * 125 + 125;
        for (int j = w * 125; j < j1; ++j) {
            float4 v = row[j];
            unsigned c = tab32[j];  // wave-uniform LDS broadcast: 4 subunit ids
            atomicAdd(&bins_e[w][c & 0xff][lane],         v.x);
            atomicAdd(&bins_e[w][(c >> 8)  & 0xff][lane], v.y);
            atomicAdd(&bins_e[w][(c >> 16) & 0xff][lane], v.z);
            atomicAdd(&bins_e[w][(c >> 24)][lane],        v.w);
        }
        // I: 500 floats/row = 125 float4; slices 32,32,32,29
        const float4*   rowi   = (const float4*)(S_i + (size_t)(b * T_DATA + t) * I_NO);
        const unsigned* tabi32 = (const unsigned*)tab_i;
        const int ji1 = min(125, w * 32 + 32);
        for (int j = w * 32; j < ji1; ++j) {
            float4 v = rowi[j];
            unsigned c = tabi32[j];
            atomicAdd(&bins_i[w][c & 0xff][lane],         v.x);
            atomicAdd(&bins_i[w][(c >> 8)  & 0xff][lane], v.y);
            atomicAdd(&bins_i[w][(c >> 16) & 0xff][lane], v.z);
            atomicAdd(&bins_i[w][(c >> 24)][lane],        v.w);
        }
    }
    __syncthreads();

    for (int i = tid; i < SUB_NO * 64; i += 256) {
        int s = i >> 6, tl = i & 63;
        if (t0 + tl < T_DATA) {
            size_t o = (size_t)(b * SUB_NO + s) * T_DATA + t0 + tl;
            syn_e[o] = bins_e[0][s][tl] + bins_e[1][s][tl] + bins_e[2][s][tl] + bins_e[3][s][tl];
            syn_i[o] = bins_i[0][s][tl] + bins_i[1][s][tl] + bins_i[2][s][tl] + bins_i[3][s][tl];
        }
    }
}

// ---------------- K2: fused IIR conv (exact alpha-kernel recurrence) + tree ----------------
// grid (ceil(T/CCHUNK), BATCH), block 256.
__global__ __launch_bounds__(256) void k_convtree(
    const float* __restrict__ syn_e, const float* __restrict__ syn_i,
    const float* __restrict__ W_syn, const float* __restrict__ Tau_syn,
    const float* __restrict__ Delta_syn, const float* __restrict__ W_sub,
    const float* __restrict__ V_o, const float* __restrict__ Theta,
    const float* __restrict__ C_den, float* __restrict__ out) {
    __shared__ float x_lds[2 * SUB_NO][XPAD];        // 40 rows (s,ch) x (warm+chunk)
    __shared__ float y_lds[SUB_NO][CCHUNK + 1];      // summed e+i filtered drive
    __shared__ float cden[SUB_NO * SUB_NO];
    __shared__ float wexp[SUB_NO];
    __shared__ float th[SUB_NO];

    const int tid = threadIdx.x;
    const int b   = blockIdx.y;
    const int t0  = blockIdx.x * CCHUNK;

    // phase 0: stage inputs
    for (int r = 0; r < 2 * SUB_NO; ++r) {
        int s = r >> 1, ch = r & 1;
        const float* src = (ch ? syn_i : syn_e) + (size_t)(b * SUB_NO + s) * T_DATA;
        for (int i = tid; i < XROW; i += 256) {
            int t = t0 - WARM + i;
            x_lds[r][i] = (t >= 0 && t < T_DATA) ? src[t] : 0.0f;
        }
    }
    for (int i = tid; i < SUB_NO * SUB_NO; i += 256) cden[i] = C_den[i];
    if (tid < SUB_NO) { wexp[tid] = expf(W_sub[tid]); th[tid] = Theta[tid]; }
    for (int i = tid; i < SUB_NO * (CCHUNK + 1); i += 256) (&y_lds[0][0])[i] = 0.0f;
    __syncthreads();

    // phase 1: 40 lanes run the 2-state IIR.
    // k[tau] = Bc*(tau-d)*r^tau for tau>=1 (k[0]=0 since d<1); exact vs FIR to ~1e-32.
    if (tid < 2 * SUB_NO) {
        int s = tid >> 1, ch = tid & 1;
        float Tp = expf(Tau_syn[s * 2 + ch]);
        float dp = expf(Delta_syn[s * 2 + ch]);
        float rr = expf(-1.0f / Tp);
        float Bc = expf(W_syn[s * 2 + ch]) * expf(dp / Tp) / Tp;
        float s1 = 0.0f, s2 = 0.0f;
        for (int i = 0; i < XROW; ++i) {
            if (i >= WARM) {
                float y = Bc * (s2 - dp * s1);   // uses x[ < t ] only (k[0]=0)
                atomicAdd(&y_lds[s][i - WARM], y);
            }
            float x = x_lds[tid][i];
            float u = s1 + x;
            s2 = rr * (s2 + u);
            s1 = rr * u;
        }
    }
    __syncthreads();

    // phase 2: per-t dendritic tree (strictly upper-triangular C_den -> exact skip of k<=s)
    if (tid < CCHUNK) {
        int tt = t0 + tid;
        if (tt < T_DATA) {
            float xs[SUB_NO];
            #pragma unroll
            for (int s = SUB_NO - 1; s >= 0; --s) {
                float leaf = 0.0f;
                #pragma unroll
                for (int k = s + 1; k < SUB_NO; ++k)
                    leaf += cden[s * SUB_NO + k] * wexp[k] * xs[k];
                xs[s] = tanhf(y_lds[s][tid] + leaf + th[s]);
            }
            out[(size_t)b * T_DATA + tt] = xs[0] * wexp[0] + V_o[0];
        }
    }
}

extern "C" void kernel_launch(void* const* d_in, const int* in_sizes, int n_in,
                              void* d_out, int out_size, void* d_ws, size_t ws_size,
                              hipStream_t stream) {
    const float* S_e       = (const float*)d_in[0];
    const float* S_i       = (const float*)d_in[1];
    const float* C_den     = (const float*)d_in[2];
    const float* C_syn_e   = (const float*)d_in[3];
    const float* C_syn_i   = (const float*)d_in[4];
    const float* W_syn     = (const float*)d_in[5];
    const float* Tau_syn   = (const float*)d_in[6];
    const float* Delta_syn = (const float*)d_in[7];
    const float* W_sub     = (const float*)d_in[8];
    const float* V_o       = (const float*)d_in[9];
    const float* Theta     = (const float*)d_in[10];
    float* out = (float*)d_out;

    size_t syn_elems = (size_t)BATCH * SUB_NO * T_DATA;
    float* syn_e_ws = (float*)d_ws;
    float* syn_i_ws = syn_e_ws + syn_elems;
    unsigned char* idx_e = (unsigned char*)(syn_i_ws + syn_elems);
    unsigned char* idx_i = idx_e + E_NO;

    hipLaunchKernelGGL(k_tables, dim3((E_NO + 255) / 256), dim3(256), 0, stream,
                       C_syn_e, C_syn_i, idx_e, idx_i);
    hipLaunchKernelGGL(k_segsum, dim3((T_DATA + 63) / 64, BATCH), dim3(256), 0, stream,
                       S_e, S_i, idx_e, idx_i, syn_e_ws, syn_i_ws);
    hipLaunchKernelGGL(k_convtree, dim3((T_DATA + CCHUNK - 1) / CCHUNK, BATCH), dim3(256), 0, stream,
                       syn_e_ws, syn_i_ws, W_syn, Tau_syn, Delta_syn, W_sub, V_o, Theta, C_den, out);
}

// Round 2
// 1103.745 us; speedup vs baseline: 1.0276x; 1.0276x over previous
//
#include <hip/hip_runtime.h>

#define SUB_NO 20
#define E_NO   2000
#define I_NO   500
#define T_NO   201
#define BATCH  4
#define T_DATA 20000

#define WARM   (T_NO - 1)      // 200
#define CCHUNK 120
#define XROW   (WARM + CCHUNK) // 320
#define XPAD   (XROW + 1)      // 321 (odd stride -> conflict-free phase-1 reads)

#define NSLOT  8               // atomic spread slots per subunit
#define BPAD   9               // bins row stride (9 coprime 32 -> conflict-free flush)

// ---------------- K0: one-hot -> index tables ----------------
__global__ void k_tables(const float* __restrict__ Ce, const float* __restrict__ Ci,
                         unsigned char* __restrict__ idx_e, unsigned char* __restrict__ idx_i) {
    int e = blockIdx.x * blockDim.x + threadIdx.x;
    if (e < E_NO) {
        int s = 0;
        for (int k = 0; k < SUB_NO; ++k) if (Ce[k * E_NO + e] != 0.0f) s = k;
        idx_e[e] = (unsigned char)s;
    }
    if (e < I_NO) {
        int s = 0;
        for (int k = 0; k < SUB_NO; ++k) if (Ci[k * I_NO + e] != 0.0f) s = k;
        idx_i[e] = (unsigned char)s;
    }
}

// ---------------- K1: segmented sum, lane = e (coalesced) ----------------
// grid (ceil(T/64), BATCH), block 256. Wave w owns 16 consecutive t's.
// Per t: stream the row with float4 loads (lane-consecutive -> 1KB/wave/instr),
// bin into per-wave LDS via ds_add_f32, flush 20 sums. No barriers in hot loop.
__global__ __launch_bounds__(256) void k_segsum(
    const float* __restrict__ S_e, const float* __restrict__ S_i,
    const unsigned char* __restrict__ idx_e, const unsigned char* __restrict__ idx_i,
    float* __restrict__ syn_e, float* __restrict__ syn_i) {
    __shared__ float bins[4][SUB_NO][BPAD];      // ~2.9 KB
    __shared__ unsigned tab_e32[E_NO / 4];       // 500 words: 4 packed ids each
    __shared__ unsigned tab_i32[I_NO / 4 + 1];   // 125 words

    const int tid  = threadIdx.x;
    const int w    = tid >> 6;
    const int lane = tid & 63;
    const int slot = lane & (NSLOT - 1);
    const int b    = blockIdx.y;
    const int t0   = blockIdx.x * 64 + w * 16;

    const unsigned* ge = (const unsigned*)idx_e;
    for (int i = tid; i < E_NO / 4; i += 256) tab_e32[i] = ge[i];
    const unsigned* gi = (const unsigned*)idx_i;
    for (int i = tid; i < I_NO / 4 + 1; i += 256)
        tab_i32[i] = (i < I_NO / 4 + (I_NO % 4 ? 1 : 0)) ? gi[i] : 0u;
    __syncthreads();

    float* binw = &bins[w][0][0];

    for (int i = 0; i < 16; ++i) {
        int t = t0 + i;
        if (t >= T_DATA) break;

        // ---- E pass ----
        for (int k = lane; k < SUB_NO * BPAD; k += 64) binw[k] = 0.0f;
        const float4* row = (const float4*)(S_e + (size_t)(b * T_DATA + t) * E_NO);
        for (int j = lane; j < E_NO / 4; j += 64) {
            float4 v = row[j];
            unsigned c = tab_e32[j];
            atomicAdd(binw + (c & 0xff)         * BPAD + slot, v.x);
            atomicAdd(binw + ((c >> 8)  & 0xff) * BPAD + slot, v.y);
            atomicAdd(binw + ((c >> 16) & 0xff) * BPAD + slot, v.z);
            atomicAdd(binw + ((c >> 24))        * BPAD + slot, v.w);
        }
        if (lane < SUB_NO) {
            float s = 0.0f;
            #pragma unroll
            for (int k = 0; k < NSLOT; ++k) s += binw[lane * BPAD + k];
            syn_e[(size_t)(b * SUB_NO + lane) * T_DATA + t] = s;
        }

        // ---- I pass ----
        for (int k = lane; k < SUB_NO * BPAD; k += 64) binw[k] = 0.0f;
        const float4* rowi = (const float4*)(S_i + (size_t)(b * T_DATA + t) * I_NO);
        for (int j = lane; j < I_NO / 4; j += 64) {
            float4 v = rowi[j];
            unsigned c = tab_i32[j];
            atomicAdd(binw + (c & 0xff)         * BPAD + slot, v.x);
            atomicAdd(binw + ((c >> 8)  & 0xff) * BPAD + slot, v.y);
            atomicAdd(binw + ((c >> 16) & 0xff) * BPAD + slot, v.z);
            atomicAdd(binw + ((c >> 24))        * BPAD + slot, v.w);
        }
        if (lane < SUB_NO) {
            float s = 0.0f;
            #pragma unroll
            for (int k = 0; k < NSLOT; ++k) s += binw[lane * BPAD + k];
            syn_i[(size_t)(b * SUB_NO + lane) * T_DATA + t] = s;
        }
    }
}

// ---------------- K2: fused IIR conv (exact alpha-kernel recurrence) + tree ----------------
// grid (ceil(T/CCHUNK), BATCH), block 256.
__global__ __launch_bounds__(256) void k_convtree(
    const float* __restrict__ syn_e, const float* __restrict__ syn_i,
    const float* __restrict__ W_syn, const float* __restrict__ Tau_syn,
    const float* __restrict__ Delta_syn, const float* __restrict__ W_sub,
    const float* __restrict__ V_o, const float* __restrict__ Theta,
    const float* __restrict__ C_den, float* __restrict__ out) {
    __shared__ float x_lds[2 * SUB_NO][XPAD];    // 40 rows (s,ch) x (warm+chunk): 51.4 KB
    __shared__ float y2[2 * SUB_NO][CCHUNK + 1]; // per-row filtered drive: 19.4 KB
    __shared__ float cden[SUB_NO * SUB_NO];
    __shared__ float wexp[SUB_NO];
    __shared__ float th[SUB_NO];

    const int tid = threadIdx.x;
    const int b   = blockIdx.y;
    const int t0  = blockIdx.x * CCHUNK;

    // phase 0: stage inputs (rows are contiguous in [b][s][t] layout -> coalesced)
    for (int r = 0; r < 2 * SUB_NO; ++r) {
        int s = r >> 1, ch = r & 1;
        const float* src = (ch ? syn_i : syn_e) + (size_t)(b * SUB_NO + s) * T_DATA;
        for (int i = tid; i < XROW; i += 256) {
            int t = t0 - WARM + i;
            x_lds[r][i] = (t >= 0 && t < T_DATA) ? src[t] : 0.0f;
        }
    }
    for (int i = tid; i < SUB_NO * SUB_NO; i += 256) cden[i] = C_den[i];
    if (tid < SUB_NO) { wexp[tid] = expf(W_sub[tid]); th[tid] = Theta[tid]; }
    __syncthreads();

    // phase 1: 40 lanes run the 2-state IIR.
    // k[tau] = Bc*(tau-d)*r^tau for tau>=1 (k[0]=0 since d<1); truncation ~r^200 ~ 1e-32.
    if (tid < 2 * SUB_NO) {
        int s = tid >> 1, ch = tid & 1;
        float Tp = expf(Tau_syn[s * 2 + ch]);
        float dp = expf(Delta_syn[s * 2 + ch]);
        float rr = expf(-1.0f / Tp);
        float Bc = expf(W_syn[s * 2 + ch]) * expf(dp / Tp) / Tp;
        float s1 = 0.0f, s2 = 0.0f;
        for (int i = 0; i < WARM; ++i) {          // warm-up: ingest only
            float u = s1 + x_lds[tid][i];
            s2 = rr * (s2 + u);
            s1 = rr * u;
        }
        for (int i = WARM; i < XROW; ++i) {       // output region
            y2[tid][i - WARM] = Bc * (s2 - dp * s1);  // state = f(x[<t]) only (k[0]=0)
            float u = s1 + x_lds[tid][i];
            s2 = rr * (s2 + u);
            s1 = rr * u;
        }
    }
    __syncthreads();

    // phase 2: per-t dendritic tree (strictly upper-triangular C_den -> exact skip of k<=s)
    if (tid < CCHUNK) {
        int tt = t0 + tid;
        if (tt < T_DATA) {
            float xs[SUB_NO];
            #pragma unroll
            for (int s = SUB_NO - 1; s >= 0; --s) {
                float leaf = 0.0f;
                #pragma unroll
                for (int k = s + 1; k < SUB_NO; ++k)
                    leaf += cden[s * SUB_NO + k] * wexp[k] * xs[k];
                xs[s] = tanhf(y2[2 * s][tid] + y2[2 * s + 1][tid] + leaf + th[s]);
            }
            out[(size_t)b * T_DATA + tt] = xs[0] * wexp[0] + V_o[0];
        }
    }
}

extern "C" void kernel_launch(void* const* d_in, const int* in_sizes, int n_in,
                              void* d_out, int out_size, void* d_ws, size_t ws_size,
                              hipStream_t stream) {
    const float* S_e       = (const float*)d_in[0];
    const float* S_i       = (const float*)d_in[1];
    const float* C_den     = (const float*)d_in[2];
    const float* C_syn_e   = (const float*)d_in[3];
    const float* C_syn_i   = (const float*)d_in[4];
    const float* W_syn     = (const float*)d_in[5];
    const float* Tau_syn   = (const float*)d_in[6];
    const float* Delta_syn = (const float*)d_in[7];
    const float* W_sub     = (const float*)d_in[8];
    const float* V_o       = (const float*)d_in[9];
    const float* Theta     = (const float*)d_in[10];
    float* out = (float*)d_out;

    size_t syn_elems = (size_t)BATCH * SUB_NO * T_DATA;
    float* syn_e_ws = (float*)d_ws;
    float* syn_i_ws = syn_e_ws + syn_elems;
    unsigned char* idx_e = (unsigned char*)(syn_i_ws + syn_elems);
    unsigned char* idx_i = idx_e + E_NO;

    hipLaunchKernelGGL(k_tables, dim3((E_NO + 255) / 256), dim3(256), 0, stream,
                       C_syn_e, C_syn_i, idx_e, idx_i);
    hipLaunchKernelGGL(k_segsum, dim3((T_DATA + 63) / 64, BATCH), dim3(256), 0, stream,
                       S_e, S_i, idx_e, idx_i, syn_e_ws, syn_i_ws);
    hipLaunchKernelGGL(k_convtree, dim3((T_DATA + CCHUNK - 1) / CCHUNK, BATCH), dim3(256), 0, stream,
                       syn_e_ws, syn_i_ws, W_syn, Tau_syn, Delta_syn, W_sub, V_o, Theta, C_den, out);
}

// Round 3
// 248.068 us; speedup vs baseline: 4.5723x; 4.4494x over previous
//
#include <hip/hip_runtime.h>

#define SUB_NO 20
#define E_NO   2000
#define I_NO   500
#define T_NO   201
#define BATCH  4
#define T_DATA 20000

#define WARM   (T_NO - 1)      // 200
#define CCHUNK 120
#define XROW   (WARM + CCHUNK) // 320
#define XPAD   (XROW + 1)

// GEMM geometry: per-wave 32-t tile, e-chunks of 64 (K padded: E->2048, I->512)
#define NC_E   32
#define NC_I   8
#define NKS_E  (NC_E * 2)      // mfma K-steps (K=32 each)
#define NKS_I  (NC_I * 2)
#define SLAB_USH 2176          // 32 rows x 68 ushort (64 bf16 + 4 pad)

typedef unsigned short ush;
typedef short  bf16x8 __attribute__((ext_vector_type(8)));
typedef float  f32x4  __attribute__((ext_vector_type(4)));

__device__ __forceinline__ ush f2bf(float f) {   // RTNE fp32 -> bf16 (no NaN in data)
    unsigned u = __float_as_uint(f);
    u += 0x7FFFu + ((u >> 16) & 1u);
    return (ush)(u >> 16);
}

// ---------------- K0a: one-hot -> index tables ----------------
__global__ void k_tables(const float* __restrict__ Ce, const float* __restrict__ Ci,
                         unsigned char* __restrict__ idx_e, unsigned char* __restrict__ idx_i) {
    int e = blockIdx.x * blockDim.x + threadIdx.x;
    if (e < E_NO) {
        int s = 0;
        for (int k = 0; k < SUB_NO; ++k) if (Ce[k * E_NO + e] != 0.0f) s = k;
        idx_e[e] = (unsigned char)s;
    }
    if (e < I_NO) {
        int s = 0;
        for (int k = 0; k < SUB_NO; ++k) if (Ci[k * I_NO + e] != 0.0f) s = k;
        idx_i[e] = (unsigned char)s;
    }
}

// ---------------- K0b: build bf16 one-hot A-operand fragments ----------------
// mfma_f32_16x16x32_bf16 A layout: lane holds A[row = lane&15][k = (lane>>4)*8 + j], j=0..7.
// Afrag[(rt*nks + kstep)*64 + lane][8], row = rt*16 + (lane&15), k = kstep*32 + (lane>>4)*8 + j.
__global__ void k_build_afrag(const unsigned char* __restrict__ idx_e,
                              const unsigned char* __restrict__ idx_i,
                              ush* __restrict__ Ae, ush* __restrict__ Ai) {
    int g = blockIdx.x * 256 + threadIdx.x;
    int isE = g < 2 * NKS_E * 64;
    int rem = isE ? g : g - 2 * NKS_E * 64;
    if (!isE && rem >= 2 * NKS_I * 64) return;
    int nks = isE ? NKS_E : NKS_I;
    int KD  = isE ? E_NO : I_NO;
    const unsigned char* idx = isE ? idx_e : idx_i;
    int lane = rem & 63, kstep = (rem >> 6) % nks, rt = (rem >> 6) / nks;
    int row = rt * 16 + (lane & 15), hi = lane >> 4;
    ush* dst = (isE ? Ae : Ai) + (size_t)rem * 8;
    #pragma unroll
    for (int j = 0; j < 8; ++j) {
        int k = kstep * 32 + hi * 8 + j;
        dst[j] = (k < KD && idx[k] == row) ? (ush)0x3F80 : (ush)0;
    }
}

// ---------------- K1: projection as bf16 MFMA GEMM (no atomics, no barriers) ----------------
__device__ __forceinline__ void run_phase(const float* __restrict__ src, int KD,
        const bf16x8* __restrict__ Af, int nks, int nc,
        ush* __restrict__ sl0, int bT, int t0, int lane, f32x4 acc[2][2]) {
    const int KD4 = KD >> 2;
    float4 stage[8];
    #pragma unroll
    for (int i = 0; i < 8; ++i) {                    // prefetch chunk 0
        int slot = i * 64 + lane, r = slot >> 4, q = slot & 15;
        const float4* rp = (const float4*)(src + (size_t)(bT + t0 + r) * KD);
        stage[i] = rp[q < KD4 ? q : KD4 - 1];
    }
    for (int c = 0; c < nc; ++c) {
        ush* sl = sl0 + (c & 1) * SLAB_USH;
        #pragma unroll
        for (int i = 0; i < 8; ++i) {                // cvt + stage chunk c into LDS
            int slot = i * 64 + lane, r = slot >> 4, q = slot & 15;
            float4 v = stage[i];
            *(ushort4*)(sl + r * 68 + q * 4) =
                make_ushort4(f2bf(v.x), f2bf(v.y), f2bf(v.z), f2bf(v.w));
        }
        if (c + 1 < nc) {                            // issue chunk c+1 loads (fly over MFMA)
            #pragma unroll
            for (int i = 0; i < 8; ++i) {
                int slot = i * 64 + lane, r = slot >> 4, q = slot & 15;
                const float4* rp = (const float4*)(src + (size_t)(bT + t0 + r) * KD);
                int f4 = (c + 1) * 16 + q;           // clamp: pad-K reads dup last f4; A=0 there
                stage[i] = rp[f4 < KD4 ? f4 : KD4 - 1];
            }
        }
        #pragma unroll
        for (int ks = 0; ks < 2; ++ks) {
            int kstep = c * 2 + ks;
            bf16x8 a0 = Af[(size_t)(0 * nks + kstep) * 64 + lane];   // L2-resident
            bf16x8 a1 = Af[(size_t)(1 * nks + kstep) * 64 + lane];
            #pragma unroll
            for (int ct = 0; ct < 2; ++ct) {
                // B layout: lane holds B[k = (lane>>4)*8+j][col = lane&15]
                const ush* p = sl + (ct * 16 + (lane & 15)) * 68 + ks * 32 + (lane >> 4) * 8;
                union { uint2 u2[2]; bf16x8 v; } fu;
                fu.u2[0] = *(const uint2*)p;
                fu.u2[1] = *(const uint2*)(p + 4);
                acc[0][ct] = __builtin_amdgcn_mfma_f32_16x16x32_bf16(a0, fu.v, acc[0][ct], 0, 0, 0);
                acc[1][ct] = __builtin_amdgcn_mfma_f32_16x16x32_bf16(a1, fu.v, acc[1][ct], 0, 0, 0);
            }
        }
    }
}

__device__ __forceinline__ void store_acc(float* __restrict__ dst, f32x4 acc[2][2],
                                          int b, int t0, int lane) {
    #pragma unroll
    for (int rt = 0; rt < 2; ++rt)
        #pragma unroll
        for (int ct = 0; ct < 2; ++ct)
            #pragma unroll
            for (int r = 0; r < 4; ++r) {
                int s = rt * 16 + (lane >> 4) * 4 + r;   // C/D: col=lane&15, row=(lane>>4)*4+reg
                if (s < SUB_NO)
                    dst[((size_t)b * SUB_NO + s) * T_DATA + t0 + ct * 16 + (lane & 15)] =
                        acc[rt][ct][r];
            }
}

__global__ __launch_bounds__(256) void k_proj(
        const float* __restrict__ S_e, const float* __restrict__ S_i,
        const ush* __restrict__ Ae, const ush* __restrict__ Ai,
        float* __restrict__ syn_e, float* __restrict__ syn_i) {
    __shared__ __align__(16) ush slab[4][2][SLAB_USH];   // per-wave private double-buffer
    const int tid = threadIdx.x, w = tid >> 6, lane = tid & 63;
    const int tile = blockIdx.x * 4 + w;
    if (tile >= T_DATA / 32) return;                     // no __syncthreads in this kernel
    const int b = blockIdx.y, t0 = tile * 32, bT = b * T_DATA;

    f32x4 acc[2][2];
    #pragma unroll
    for (int rt = 0; rt < 2; ++rt)
        #pragma unroll
        for (int ct = 0; ct < 2; ++ct) { f32x4 z = {0.f, 0.f, 0.f, 0.f}; acc[rt][ct] = z; }
    run_phase(S_e, E_NO, (const bf16x8*)Ae, NKS_E, NC_E, &slab[w][0][0], bT, t0, lane, acc);
    store_acc(syn_e, acc, b, t0, lane);

    #pragma unroll
    for (int rt = 0; rt < 2; ++rt)
        #pragma unroll
        for (int ct = 0; ct < 2; ++ct) { f32x4 z = {0.f, 0.f, 0.f, 0.f}; acc[rt][ct] = z; }
    run_phase(S_i, I_NO, (const bf16x8*)Ai, NKS_I, NC_I, &slab[w][0][0], bT, t0, lane, acc);
    store_acc(syn_i, acc, b, t0, lane);
}

// ---------------- K2: fused IIR conv (exact alpha-kernel recurrence) + tree ----------------
__global__ __launch_bounds__(256) void k_convtree(
    const float* __restrict__ syn_e, const float* __restrict__ syn_i,
    const float* __restrict__ W_syn, const float* __restrict__ Tau_syn,
    const float* __restrict__ Delta_syn, const float* __restrict__ W_sub,
    const float* __restrict__ V_o, const float* __restrict__ Theta,
    const float* __restrict__ C_den, float* __restrict__ out) {
    __shared__ float x_lds[2 * SUB_NO][XPAD];
    __shared__ float y2[2 * SUB_NO][CCHUNK + 1];
    __shared__ float cden[SUB_NO * SUB_NO];
    __shared__ float wexp[SUB_NO];
    __shared__ float th[SUB_NO];

    const int tid = threadIdx.x;
    const int b   = blockIdx.y;
    const int t0  = blockIdx.x * CCHUNK;

    for (int r = 0; r < 2 * SUB_NO; ++r) {
        int s = r >> 1, ch = r & 1;
        const float* src = (ch ? syn_i : syn_e) + (size_t)(b * SUB_NO + s) * T_DATA;
        for (int i = tid; i < XROW; i += 256) {
            int t = t0 - WARM + i;
            x_lds[r][i] = (t >= 0 && t < T_DATA) ? src[t] : 0.0f;
        }
    }
    for (int i = tid; i < SUB_NO * SUB_NO; i += 256) cden[i] = C_den[i];
    if (tid < SUB_NO) { wexp[tid] = expf(W_sub[tid]); th[tid] = Theta[tid]; }
    __syncthreads();

    if (tid < 2 * SUB_NO) {
        int s = tid >> 1, ch = tid & 1;
        float Tp = expf(Tau_syn[s * 2 + ch]);
        float dp = expf(Delta_syn[s * 2 + ch]);
        float rr = expf(-1.0f / Tp);
        float Bc = expf(W_syn[s * 2 + ch]) * expf(dp / Tp) / Tp;
        float s1 = 0.0f, s2 = 0.0f;
        for (int i = 0; i < WARM; ++i) {
            float u = s1 + x_lds[tid][i];
            s2 = rr * (s2 + u);
            s1 = rr * u;
        }
        for (int i = WARM; i < XROW; ++i) {
            y2[tid][i - WARM] = Bc * (s2 - dp * s1);
            float u = s1 + x_lds[tid][i];
            s2 = rr * (s2 + u);
            s1 = rr * u;
        }
    }
    __syncthreads();

    if (tid < CCHUNK) {
        int tt = t0 + tid;
        if (tt < T_DATA) {
            float xs[SUB_NO];
            #pragma unroll
            for (int s = SUB_NO - 1; s >= 0; --s) {
                float leaf = 0.0f;
                #pragma unroll
                for (int k = s + 1; k < SUB_NO; ++k)
                    leaf += cden[s * SUB_NO + k] * wexp[k] * xs[k];
                xs[s] = tanhf(y2[2 * s][tid] + y2[2 * s + 1][tid] + leaf + th[s]);
            }
            out[(size_t)b * T_DATA + tt] = xs[0] * wexp[0] + V_o[0];
        }
    }
}

extern "C" void kernel_launch(void* const* d_in, const int* in_sizes, int n_in,
                              void* d_out, int out_size, void* d_ws, size_t ws_size,
                              hipStream_t stream) {
    const float* S_e       = (const float*)d_in[0];
    const float* S_i       = (const float*)d_in[1];
    const float* C_den     = (const float*)d_in[2];
    const float* C_syn_e   = (const float*)d_in[3];
    const float* C_syn_i   = (const float*)d_in[4];
    const float* W_syn     = (const float*)d_in[5];
    const float* Tau_syn   = (const float*)d_in[6];
    const float* Delta_syn = (const float*)d_in[7];
    const float* W_sub     = (const float*)d_in[8];
    const float* V_o       = (const float*)d_in[9];
    const float* Theta     = (const float*)d_in[10];
    float* out = (float*)d_out;

    size_t syn_elems = (size_t)BATCH * SUB_NO * T_DATA;       // 1.6M floats each
    float* syn_e_ws = (float*)d_ws;
    float* syn_i_ws = syn_e_ws + syn_elems;
    ush*   Ae       = (ush*)(syn_i_ws + syn_elems);           // 2*64*64*8 ush = 128 KiB
    ush*   Ai       = Ae + (size_t)2 * NKS_E * 64 * 8;        // 2*16*64*8 ush = 32 KiB
    unsigned char* idx_e = (unsigned char*)(Ai + (size_t)2 * NKS_I * 64 * 8);
    unsigned char* idx_i = idx_e + E_NO;

    hipLaunchKernelGGL(k_tables, dim3((E_NO + 255) / 256), dim3(256), 0, stream,
                       C_syn_e, C_syn_i, idx_e, idx_i);
    hipLaunchKernelGGL(k_build_afrag, dim3((2 * NKS_E * 64 + 2 * NKS_I * 64 + 255) / 256),
                       dim3(256), 0, stream, idx_e, idx_i, Ae, Ai);
    hipLaunchKernelGGL(k_proj, dim3((T_DATA / 32 + 3) / 4, BATCH), dim3(256), 0, stream,
                       S_e, S_i, Ae, Ai, syn_e_ws, syn_i_ws);
    hipLaunchKernelGGL(k_convtree, dim3((T_DATA + CCHUNK - 1) / CCHUNK, BATCH), dim3(256), 0, stream,
                       syn_e_ws, syn_i_ws, W_syn, Tau_syn, Delta_syn, W_sub, V_o, Theta, C_den, out);
}